// Round 3
// baseline (488.374 us; speedup 1.0000x reference)
//
#include <hip/hip_runtime.h>
#include <hip/hip_bf16.h>

typedef __attribute__((ext_vector_type(8))) short bf16x8;
typedef __attribute__((ext_vector_type(8))) unsigned short u16x8;
typedef __attribute__((ext_vector_type(4))) float f32x4;

#define BM 128
#define BN 128
#define BK 64

__device__ __forceinline__ unsigned short f2b(float f) {
    union { float f; unsigned int u; } x; x.f = f;
    unsigned int r = x.u + 0x7fffu + ((x.u >> 16) & 1u);
    return (unsigned short)(r >> 16);
}
__device__ __forceinline__ float b2f(unsigned short b) {
    union { unsigned int u; float f; } x; x.u = ((unsigned int)b) << 16;
    return x.f;
}
__device__ __forceinline__ float sigmoidf_(float v) {
    return 1.0f / (1.0f + __expf(-v));
}
__device__ __forceinline__ float tanhf_(float v) {
    return 1.0f - 2.0f / (__expf(2.0f * v) + 1.0f);
}

__device__ __forceinline__ void gll16(const void* g, void* l) {
    __builtin_amdgcn_global_load_lds(
        (const __attribute__((address_space(1))) void*)g,
        (__attribute__((address_space(3))) void*)l,
        16, 0, 0);
}

// ===================== GEMM1: 128x256 tile, 8 waves, 2 blocks/CU =====================
// S = Xall(8192x4096) @ Wcat(3072x4096)^T, fused gate epilogues.
// Round-0's proven drain-loop structure (4x 64x64-wave-tile TLP mechanism) kept; only the
// block geometry widened: 8 waves (2M x 4N of 64x64), LDS 48KB -> 2 blocks/CU (16 waves/CU,
// same wave-level TLP as round 0's 4x4-wave blocks), A-traffic per output halved,
// staging 6 gll16/thread (was 8).
// Grid 1024 flat blocks; xcd = f&7:
//   p even: r/z.  bn = xcd (each XCD owns one 2MB B-panel -> L2-resident), bm = p>>1, nk=64.
//   p odd : h split-K (2 slices x 24 k-tiles -> shp0/shp1; gemm2 sums them). bnh = xcd>>1,
//           slice = xcd&1 (0.75MB B-slice L2-resident), k>=16 remaps +1024 (dead Uh seg).
// Even/odd interleave gives every CU a {64,24,24}-unit job mix -> ~88-unit makespan.
// LDS XOR swizzle as round 0 (phys 16B-block p of row r holds global block p^(r&7)):
// SQ_LDS_BANK_CONFLICT == 0 verified rounds 0-2.
__global__ __launch_bounds__(512, 4) void gemm1(
    const unsigned short* __restrict__ Xall,
    const unsigned short* __restrict__ Wcat,
    const float* __restrict__ hprev,
    const float* __restrict__ br, const float* __restrict__ bz,
    unsigned short* __restrict__ rh,    // bf16 8192x1024
    unsigned short* __restrict__ zs,    // bf16 8192x1024
    unsigned short* __restrict__ shp0,  // bf16 8192x1024 (h preact, K-slice 0)
    unsigned short* __restrict__ shp1)  // bf16 8192x1024 (h preact, K-slice 1)
{
    __shared__ __attribute__((aligned(16))) unsigned short As[128 * BK];  // 16 KB
    __shared__ __attribute__((aligned(16))) unsigned short Bs[256 * BK];  // 32 KB
    f32x4 acc[4][4] = {};

    const int f = blockIdx.x;
    const int xcd = f & 7;
    const int p = f >> 3;                  // 0..127
    const int bm = p >> 1;                 // 0..63
    int n0, nkt, tstart, rfrom, slice = 0;
    const int hgate = p & 1;
    if (!hgate) {                          // r/z
        n0 = xcd * 256; nkt = 64; tstart = 0; rfrom = 1 << 30;
    } else {                               // h, split-K
        const int bnh = xcd >> 1; slice = xcd & 1;
        n0 = 2048 + bnh * 256; nkt = 24; tstart = slice * 24; rfrom = 16;
    }
    const int m0 = bm * 128;

    const int t = threadIdx.x;
    const int lane = t & 63;
    const int w = t >> 6;
    const int wm = w >> 2, wn = w & 3;     // 2 x 4 waves, wave tile 64x64
    const int srow = t >> 3;               // 0..63
    const int ldsCol = (t & 7) * 8;
    const int swc = ((t & 7) ^ (srow & 7)) * 8;

    const unsigned short* gA = Xall + (size_t)(m0 + srow) * 4096 + swc;
    const unsigned short* gB = Wcat + (size_t)(n0 + srow) * 4096 + swc;

    for (int kt = 0; kt < nkt; ++kt) {
        const int kp = tstart + kt;
        const int k0 = kp * 64 + (kp >= rfrom ? 1024 : 0);
        __syncthreads();
        // A: 128 rows (2 sweeps), B: 256 rows (4 sweeps); 6 x 16B per thread.
        gll16(gA + k0, As + srow * BK + ldsCol);
        gll16(gA + (size_t)64 * 4096 + k0, As + (64 + srow) * BK + ldsCol);
        #pragma unroll
        for (int j = 0; j < 4; ++j)
            gll16(gB + (size_t)(j * 64) * 4096 + k0, Bs + (j * 64 + srow) * BK + ldsCol);
        __syncthreads();                   // implies vmcnt(0): tile resident
        #pragma unroll
        for (int kk = 0; kk < 2; ++kk) {
            bf16x8 af[4], bfr[4];
            // fragment row r has r&7 == lane&7 -> swizzle term is (lane&7)
            const int off = ((kk * 4 + (lane >> 4)) ^ (lane & 7)) * 8;
            const int ra = (wm * 64 + (lane & 15)) * BK + off;
            const int rb = (wn * 64 + (lane & 15)) * BK + off;
            #pragma unroll
            for (int i = 0; i < 4; ++i)
                af[i] = *(const bf16x8*)(As + ra + i * 16 * BK);
            #pragma unroll
            for (int j = 0; j < 4; ++j)
                bfr[j] = *(const bf16x8*)(Bs + rb + j * 16 * BK);
            #pragma unroll
            for (int i = 0; i < 4; ++i)
                #pragma unroll
                for (int j = 0; j < 4; ++j)
                    acc[i][j] = __builtin_amdgcn_mfma_f32_16x16x32_bf16(
                        af[i], bfr[j], acc[i][j], 0, 0, 0);
        }
    }

    // ---------- epilogue (round-0 form, 64x64 wave tile) ----------
    const int rowb = m0 + wm * 64 + (lane >> 4) * 4;
    if (!hgate) {
        const int gate = xcd >> 2;                     // 0=r (xcd 0-3), 1=z (xcd 4-7)
        const int colb = (n0 - gate * 1024) + wn * 64 + (lane & 15);
        if (gate == 0) {
            #pragma unroll
            for (int i = 0; i < 4; ++i)
                #pragma unroll
                for (int r = 0; r < 4; ++r) {
                    const int m = rowb + i * 16 + r;
                    #pragma unroll
                    for (int j = 0; j < 4; ++j) {
                        const int n = colb + j * 16;
                        const size_t idx = (size_t)m * 1024 + n;
                        const float rr = sigmoidf_(acc[i][j][r] + br[n]);
                        rh[idx] = f2b(rr * hprev[idx]);
                    }
                }
        } else {
            #pragma unroll
            for (int i = 0; i < 4; ++i)
                #pragma unroll
                for (int r = 0; r < 4; ++r) {
                    const int m = rowb + i * 16 + r;
                    #pragma unroll
                    for (int j = 0; j < 4; ++j) {
                        const int n = colb + j * 16;
                        const size_t idx = (size_t)m * 1024 + n;
                        zs[idx] = f2b(sigmoidf_(acc[i][j][r] + bz[n]));
                    }
                }
        }
    } else {
        unsigned short* __restrict__ dst = slice ? shp1 : shp0;
        const int colb = (n0 - 2048) + wn * 64 + (lane & 15);
        #pragma unroll
        for (int i = 0; i < 4; ++i)
            #pragma unroll
            for (int r = 0; r < 4; ++r) {
                const int m = rowb + i * 16 + r;
                #pragma unroll
                for (int j = 0; j < 4; ++j) {
                    const int n = colb + j * 16;
                    dst[(size_t)m * 1024 + n] = f2b(acc[i][j][r]);
                }
            }
    }
}

// ===================== GEMM2: round-0 128x128 core (verified) =====================
__device__ __forceinline__ void mma_core(
    const unsigned short* __restrict__ A, int lda,
    const unsigned short* __restrict__ B, int ldb,
    int m0, int n0, int nk,
    unsigned short* As, unsigned short* Bs, f32x4 acc[4][4])
{
    const int t = threadIdx.x;
    const int lane = t & 63;
    const int wm = (t >> 7) & 1;
    const int wn = (t >> 6) & 1;
    const int srow = t >> 3;
    const int ldsCol = (t & 7) * 8;
    const int swc = (((t & 7) ^ ((t >> 3) & 7))) * 8;

    for (int kt = 0; kt < nk; ++kt) {
        int k0 = kt * BK;
        __syncthreads();
        #pragma unroll
        for (int j = 0; j < 4; ++j) {
            int row = j * 32 + srow;
            gll16(A + (size_t)(m0 + row) * lda + k0 + swc, As + row * BK + ldsCol);
            gll16(B + (size_t)(n0 + row) * ldb + k0 + swc, Bs + row * BK + ldsCol);
        }
        __syncthreads();
        #pragma unroll
        for (int kk = 0; kk < 2; ++kk) {
            bf16x8 af[4], bfr[4];
            const int off = (((kk * 4 + (lane >> 4)) ^ (lane & 7))) * 8;
            const int ra = (wm * 64 + (lane & 15)) * BK + off;
            const int rb = (wn * 64 + (lane & 15)) * BK + off;
            #pragma unroll
            for (int i = 0; i < 4; ++i)
                af[i] = *(const bf16x8*)(As + ra + i * 16 * BK);
            #pragma unroll
            for (int j = 0; j < 4; ++j)
                bfr[j] = *(const bf16x8*)(Bs + rb + j * 16 * BK);
            #pragma unroll
            for (int i = 0; i < 4; ++i)
                #pragma unroll
                for (int j = 0; j < 4; ++j)
                    acc[i][j] = __builtin_amdgcn_mfma_f32_16x16x32_bf16(
                        af[i], bfr[j], acc[i][j], 0, 0, 0);
        }
    }
}

// GEMM2: Sh2 = rh(8192x1024) @ Uhb(1024x1024)^T; out = z*tanh(Sh2+shp0+shp1+bh)+(1-z)*h.
__global__ __launch_bounds__(256, 4) void gemm2(
    const unsigned short* __restrict__ rh,
    const unsigned short* __restrict__ Uhb,
    const unsigned short* __restrict__ shp0,
    const unsigned short* __restrict__ shp1,
    const float* __restrict__ bh,
    const unsigned short* __restrict__ zs,
    const float* __restrict__ hprev,
    float* __restrict__ out)
{
    __shared__ __attribute__((aligned(16))) unsigned short As[BM * BK];
    __shared__ __attribute__((aligned(16))) unsigned short Bs[BN * BK];
    f32x4 acc[4][4] = {};

    const int flat = blockIdx.y * gridDim.x + blockIdx.x;
    const int xcd = flat & 7;
    const int p = flat >> 3;
    const int bm = xcd * 8 + (p & 7);
    const int bn = p >> 3;
    const int m0 = bm * BM, n0 = bn * BN;

    mma_core(rh, 1024, Uhb, 1024, m0, n0, 16, As, Bs, acc);

    const int lane = threadIdx.x & 63;
    const int wm = (threadIdx.x >> 7) & 1, wn = (threadIdx.x >> 6) & 1;
    const int rowb = m0 + wm * 64 + (lane >> 4) * 4;
    const int colb = n0 + wn * 64 + (lane & 15);

    #pragma unroll
    for (int i = 0; i < 4; ++i)
        #pragma unroll
        for (int r = 0; r < 4; ++r) {
            int m = rowb + i * 16 + r;
            #pragma unroll
            for (int j = 0; j < 4; ++j) {
                int n = colb + j * 16;
                size_t idx = (size_t)m * 1024 + n;
                float val = acc[i][j][r] + b2f(shp0[idx]) + b2f(shp1[idx]) + bh[n];
                float hp = tanhf_(val);
                float zv = b2f(zs[idx]);
                out[idx] = zv * hp + (1.0f - zv) * hprev[idx];
            }
        }
}

// fp32 -> bf16 strided copy-cast, 12 jobs, flat-indexed (load-balanced).
struct CastJobs {
    const float* src[12];
    unsigned short* dst[12];
    int start[13];
    int cs3[12];
    int stride[12];
};

__global__ __launch_bounds__(256) void cast_all(CastJobs jb, int total) {
    for (int i = blockIdx.x * blockDim.x + threadIdx.x; i < total;
         i += gridDim.x * blockDim.x) {
        int j = 0;
        #pragma unroll
        for (int k = 1; k < 12; ++k) j += (i >= jb.start[k]) ? 1 : 0;
        const int li = i - jb.start[j];
        const float4* src = (const float4*)jb.src[j];
        float4 a = src[2 * li];
        float4 b = src[2 * li + 1];
        const int cs3 = jb.cs3[j];
        int row = li >> cs3;
        int col = (li & ((1 << cs3) - 1)) * 8;
        u16x8 o;
        o[0] = f2b(a.x); o[1] = f2b(a.y); o[2] = f2b(a.z); o[3] = f2b(a.w);
        o[4] = f2b(b.x); o[5] = f2b(b.y); o[6] = f2b(b.z); o[7] = f2b(b.w);
        *(u16x8*)(jb.dst[j] + (size_t)row * jb.stride[j] + col) = o;
    }
}

extern "C" void kernel_launch(void* const* d_in, const int* in_sizes, int n_in,
                              void* d_out, int out_size, void* d_ws, size_t ws_size,
                              hipStream_t stream) {
    const float* x     = (const float*)d_in[0];
    const float* hprev = (const float*)d_in[1];
    const float* c     = (const float*)d_in[2];
    const float* Wh    = (const float*)d_in[3];
    const float* Wz    = (const float*)d_in[4];
    const float* Wr    = (const float*)d_in[5];
    const float* Uh    = (const float*)d_in[6];
    const float* Uz    = (const float*)d_in[7];
    const float* Ur    = (const float*)d_in[8];
    const float* Ch    = (const float*)d_in[9];
    const float* Cz    = (const float*)d_in[10];
    const float* Cr    = (const float*)d_in[11];
    const float* bh    = (const float*)d_in[12];
    const float* bz    = (const float*)d_in[13];
    const float* br    = (const float*)d_in[14];

    char* ws = (char*)d_ws;
    unsigned short* Xall = (unsigned short*)ws; ws += (size_t)8192 * 4096 * 2;
    unsigned short* Wcat = (unsigned short*)ws; ws += (size_t)3072 * 4096 * 2;
    unsigned short* Uhb  = (unsigned short*)ws; ws += (size_t)1024 * 1024 * 2;
    unsigned short* rhb  = (unsigned short*)ws; ws += (size_t)8192 * 1024 * 2;
    unsigned short* shp  = (unsigned short*)ws; ws += (size_t)8192 * 1024 * 2;
    unsigned short* zsb  = (unsigned short*)ws; ws += (size_t)8192 * 1024 * 2;
    unsigned short* shpB = (unsigned short*)ws; ws += (size_t)8192 * 1024 * 2;

    CastJobs jb;
    int acc = 0;
    auto setjob = [&](int j, const float* s, unsigned short* dbase, int col0,
                      int rows, int cols, int stride) {
        jb.src[j] = s; jb.dst[j] = dbase + col0;
        jb.start[j] = acc;
        acc += rows * cols / 8;
        jb.cs3[j] = (cols == 2048) ? 8 : 7;
        jb.stride[j] = stride;
    };
    // Xall = [x | hprev | c]
    setjob(0, x,     Xall, 0,    8192, 1024, 4096);
    setjob(1, hprev, Xall, 1024, 8192, 1024, 4096);
    setjob(2, c,     Xall, 2048, 8192, 2048, 4096);
    // Wcat rows 0..1023 = [Wr|Ur|Cr]
    setjob(3, Wr, Wcat, 0,    1024, 1024, 4096);
    setjob(4, Ur, Wcat, 1024, 1024, 1024, 4096);
    setjob(5, Cr, Wcat, 2048, 1024, 2048, 4096);
    // rows 1024..2047 = [Wz|Uz|Cz]
    setjob(6, Wz, Wcat + 1024 * 4096, 0,    1024, 1024, 4096);
    setjob(7, Uz, Wcat + 1024 * 4096, 1024, 1024, 1024, 4096);
    setjob(8, Cz, Wcat + 1024 * 4096, 2048, 1024, 2048, 4096);
    // rows 2048..3071 = [Wh|unused|Ch] (dead segment never read; h blocks remap k>=16 by +1024)
    setjob(9,  Wh, Wcat + 2048 * 4096, 0,    1024, 1024, 4096);
    setjob(10, Ch, Wcat + 2048 * 4096, 2048, 1024, 2048, 4096);
    // Uh standalone
    setjob(11, Uh, Uhb, 0, 1024, 1024, 1024);
    jb.start[12] = acc;

    hipLaunchKernelGGL(cast_all, dim3(2048), dim3(256), 0, stream, jb, acc);
    hipLaunchKernelGGL(gemm1, dim3(1024), dim3(512), 0, stream,
                       Xall, Wcat, hprev, br, bz, rhb, zsb, shp, shpB);
    hipLaunchKernelGGL(gemm2, dim3(8, 64), dim3(256), 0, stream,
                       rhb, Uhb, shp, shpB, bh, zsb, hprev, (float*)d_out);
}

// Round 4
// 473.767 us; speedup vs baseline: 1.0308x; 1.0308x over previous
//
#include <hip/hip_runtime.h>
#include <hip/hip_bf16.h>

typedef __attribute__((ext_vector_type(8))) short bf16x8;
typedef __attribute__((ext_vector_type(8))) unsigned short u16x8;
typedef __attribute__((ext_vector_type(4))) float f32x4;

#define BM 128
#define BN 128
#define BK 64

__device__ __forceinline__ unsigned short f2b(float f) {
    union { float f; unsigned int u; } x; x.f = f;
    unsigned int r = x.u + 0x7fffu + ((x.u >> 16) & 1u);
    return (unsigned short)(r >> 16);
}
__device__ __forceinline__ float b2f(unsigned short b) {
    union { unsigned int u; float f; } x; x.u = ((unsigned int)b) << 16;
    return x.f;
}
__device__ __forceinline__ float sigmoidf_(float v) {
    return 1.0f / (1.0f + __expf(-v));
}
__device__ __forceinline__ float tanhf_(float v) {
    return 1.0f - 2.0f / (__expf(2.0f * v) + 1.0f);
}

__device__ __forceinline__ void gll16(const void* g, void* l) {
    __builtin_amdgcn_global_load_lds(
        (const __attribute__((address_space(1))) void*)g,
        (__attribute__((address_space(3))) void*)l,
        16, 0, 0);
}

// Core: C[128x128] tile of A(M x lda) * B(N x ldb)^T, both bf16 K-contiguous.
// 4 waves, each 64x64 via 4x4 grid of 16x16x32 MFMAs. This is the round-0 verified
// drain-loop core (435 us champion): 2 barriers per K-step, vmcnt(0) drain, relying on
// 4 co-resident blocks/CU at staggered K-steps to cover each other's drains (m114).
// r1-r3 lesson: every structure with fewer blocks/CU regressed on this workload.
// LDS XOR swizzle (phys 16B-block pb of row r holds global col-block pb^(r&7)):
// SQ_LDS_BANK_CONFLICT == 0 verified rounds 0-3.
// setprio(1) around the MFMA burst: blocks are phase-staggered (not lockstep) ->
// the m191 regime where prio measurably helps; m190's null was lockstep-only.
__device__ __forceinline__ void mma_core(
    const unsigned short* __restrict__ A, int lda,
    const unsigned short* __restrict__ B, int ldb,
    int m0, int n0, int nk, int kbase, int remap_from, int remap_add,
    unsigned short* As, unsigned short* Bs, f32x4 acc[4][4])
{
    const int t = threadIdx.x;
    const int lane = t & 63;
    const int wm = (t >> 7) & 1;
    const int wn = (t >> 6) & 1;
    const int srow = t >> 3;                         // staging row (0..31)
    const int ldsCol = (t & 7) * 8;                  // physical LDS col (elems)
    const int swc = (((t & 7) ^ ((t >> 3) & 7))) * 8;  // swizzled global col

    for (int kt = 0; kt < nk; ++kt) {
        int k0 = kbase + kt * BK + (kt >= remap_from ? remap_add : 0);
        __syncthreads();
        #pragma unroll
        for (int j = 0; j < 4; ++j) {
            int row = j * 32 + srow;
            gll16(A + (size_t)(m0 + row) * lda + k0 + swc, As + row * BK + ldsCol);
            gll16(B + (size_t)(n0 + row) * ldb + k0 + swc, Bs + row * BK + ldsCol);
        }
        __syncthreads();
        #pragma unroll
        for (int kk = 0; kk < 2; ++kk) {
            bf16x8 af[4], bfr[4];
            // fragment row r satisfies r&7 == lane&7, so swizzle is (lane&7)
            const int off = (((kk * 4 + (lane >> 4)) ^ (lane & 7))) * 8;
            const int ra = (wm * 64 + (lane & 15)) * BK + off;
            const int rb = (wn * 64 + (lane & 15)) * BK + off;
            #pragma unroll
            for (int i = 0; i < 4; ++i)
                af[i] = *(const bf16x8*)(As + ra + i * 16 * BK);
            #pragma unroll
            for (int j = 0; j < 4; ++j)
                bfr[j] = *(const bf16x8*)(Bs + rb + j * 16 * BK);
            __builtin_amdgcn_s_setprio(1);
            #pragma unroll
            for (int i = 0; i < 4; ++i)
                #pragma unroll
                for (int j = 0; j < 4; ++j)
                    acc[i][j] = __builtin_amdgcn_mfma_f32_16x16x32_bf16(
                        af[i], bfr[j], acc[i][j], 0, 0, 0);
            __builtin_amdgcn_s_setprio(0);
        }
    }
}

// GEMM1: S = Xall(8192x4096) @ Wcat(3072x4096)^T, fused gate epilogues.
// Round-0 geometry (128x128 tile, 256 thr, 4 blocks/CU) + h-gate split-K.
// Grid = 2048 flat blocks; xcd = f&7, p = f>>3 (256 jobs per XCD), bm = p&63:
//   p < 128 : r/z. bn = xcd*2 + (p>>6) in 0..15 (2 B-panels = 2MB per XCD, L2-resident),
//             nk = 64.
//   p >= 128: h gate SPLIT-K, slice = (p-128)>>6. bn column = xcd (n0 = 2048+xcd*128).
//             slice 0: k-tiles 0..15 (Wh) + 16..23 remapped +1024 (Ch cols 0..511).
//             slice 1: kbase 2560, k-tiles 0..23 (Ch cols 512..2047).
//             Writes shp0/shp1; gemm2 sums them (no sync needed). Verified r1-r3.
// Job lengths {64,64,24,24...}: h (short) jobs dispatch LAST -> LPT packing, smaller tail
// than round-0's mixed 48/64 tail. Per-XCD steps: 128*64 + 128*24 = 11264 (unchanged).
// (256,4): 64 VGPR + 64 AGPR = 128 regs -> exactly 4 blocks/CU (register-capped).
__global__ __launch_bounds__(256, 4) void gemm1(
    const unsigned short* __restrict__ Xall,
    const unsigned short* __restrict__ Wcat,
    const float* __restrict__ hprev,
    const float* __restrict__ br, const float* __restrict__ bz,
    unsigned short* __restrict__ rh,    // bf16 8192x1024
    unsigned short* __restrict__ zs,    // bf16 8192x1024
    unsigned short* __restrict__ shp0,  // bf16 8192x1024 (h preact, K-slice 0)
    unsigned short* __restrict__ shp1)  // bf16 8192x1024 (h preact, K-slice 1)
{
    __shared__ __attribute__((aligned(16))) unsigned short As[BM * BK];
    __shared__ __attribute__((aligned(16))) unsigned short Bs[BN * BK];
    f32x4 acc[4][4] = {};

    const int f = blockIdx.x;
    const int xcd = f & 7;
    const int p = f >> 3;                  // 0..255
    const int bm = p & 63;
    const int m0 = bm * BM;

    int n0, nkt, kbase, rfrom;
    int hslice = -1;
    if (p < 128) {                         // r/z
        const int bn = xcd * 2 + (p >> 6); // 0..15
        n0 = bn * BN; nkt = 64; kbase = 0; rfrom = 1 << 30;
    } else {                               // h, split-K
        hslice = (p - 128) >> 6;           // 0 or 1
        n0 = 2048 + xcd * BN;
        nkt = 24;
        if (hslice == 0) { kbase = 0;    rfrom = 16; }      // Wh + Ch[:,0:512]
        else             { kbase = 2560; rfrom = 1 << 30; } // Ch[:,512:2048]
    }

    mma_core(Xall, 4096, Wcat, 4096, m0, n0, nkt, kbase, rfrom, 1024, As, Bs, acc);

    const int lane = threadIdx.x & 63;
    const int wm = (threadIdx.x >> 7) & 1, wn = (threadIdx.x >> 6) & 1;
    const int rowb = m0 + wm * 64 + (lane >> 4) * 4;

    if (hslice < 0) {
        const int gate = n0 >> 10;                     // 0=r, 1=z
        const int colb = (n0 - gate * 1024) + wn * 64 + (lane & 15);
        if (gate == 0) {
            #pragma unroll
            for (int i = 0; i < 4; ++i)
                #pragma unroll
                for (int r = 0; r < 4; ++r) {
                    const int m = rowb + i * 16 + r;
                    #pragma unroll
                    for (int j = 0; j < 4; ++j) {
                        const int n = colb + j * 16;
                        const size_t idx = (size_t)m * 1024 + n;
                        const float rr = sigmoidf_(acc[i][j][r] + br[n]);
                        rh[idx] = f2b(rr * hprev[idx]);
                    }
                }
        } else {
            #pragma unroll
            for (int i = 0; i < 4; ++i)
                #pragma unroll
                for (int r = 0; r < 4; ++r) {
                    const int m = rowb + i * 16 + r;
                    #pragma unroll
                    for (int j = 0; j < 4; ++j) {
                        const int n = colb + j * 16;
                        const size_t idx = (size_t)m * 1024 + n;
                        zs[idx] = f2b(sigmoidf_(acc[i][j][r] + bz[n]));
                    }
                }
        }
    } else {
        unsigned short* __restrict__ dst = hslice ? shp1 : shp0;
        const int colb = (n0 - 2048) + wn * 64 + (lane & 15);
        #pragma unroll
        for (int i = 0; i < 4; ++i)
            #pragma unroll
            for (int r = 0; r < 4; ++r) {
                const int m = rowb + i * 16 + r;
                #pragma unroll
                for (int j = 0; j < 4; ++j) {
                    const int n = colb + j * 16;
                    dst[(size_t)m * 1024 + n] = f2b(acc[i][j][r]);
                }
            }
    }
}

// GEMM2: Sh2 = rh(8192x1024) @ Uhb(1024x1024)^T;
// epilogue: out = z*tanh(Sh2 + shp0 + shp1 + bh) + (1-z)*hprev.
__global__ __launch_bounds__(256, 4) void gemm2(
    const unsigned short* __restrict__ rh,
    const unsigned short* __restrict__ Uhb,
    const unsigned short* __restrict__ shp0,
    const unsigned short* __restrict__ shp1,
    const float* __restrict__ bh,
    const unsigned short* __restrict__ zs,
    const float* __restrict__ hprev,
    float* __restrict__ out)
{
    __shared__ __attribute__((aligned(16))) unsigned short As[BM * BK];
    __shared__ __attribute__((aligned(16))) unsigned short Bs[BN * BK];
    f32x4 acc[4][4] = {};

    const int flat = blockIdx.y * gridDim.x + blockIdx.x;
    const int xcd = flat & 7;
    const int p = flat >> 3;
    const int bm = xcd * 8 + (p & 7);
    const int bn = p >> 3;
    const int m0 = bm * BM, n0 = bn * BN;

    mma_core(rh, 1024, Uhb, 1024, m0, n0, 16, 0, 1 << 30, 0, As, Bs, acc);

    const int lane = threadIdx.x & 63;
    const int wm = (threadIdx.x >> 7) & 1, wn = (threadIdx.x >> 6) & 1;
    const int rowb = m0 + wm * 64 + (lane >> 4) * 4;
    const int colb = n0 + wn * 64 + (lane & 15);

    #pragma unroll
    for (int i = 0; i < 4; ++i)
        #pragma unroll
        for (int r = 0; r < 4; ++r) {
            int m = rowb + i * 16 + r;
            #pragma unroll
            for (int j = 0; j < 4; ++j) {
                int n = colb + j * 16;
                size_t idx = (size_t)m * 1024 + n;
                float val = acc[i][j][r] + b2f(shp0[idx]) + b2f(shp1[idx]) + bh[n];
                float hp = tanhf_(val);
                float zv = b2f(zs[idx]);
                out[idx] = zv * hp + (1.0f - zv) * hprev[idx];
            }
        }
}

// fp32 -> bf16 strided copy-cast, 12 jobs, flat-indexed (load-balanced).
struct CastJobs {
    const float* src[12];
    unsigned short* dst[12];   // pre-offset by dst col0
    int start[13];             // prefix sums in n8 units
    int cs3[12];               // log2(src cols) - 3
    int stride[12];            // dst row stride in elements
};

__global__ __launch_bounds__(256) void cast_all(CastJobs jb, int total) {
    for (int i = blockIdx.x * blockDim.x + threadIdx.x; i < total;
         i += gridDim.x * blockDim.x) {
        int j = 0;
        #pragma unroll
        for (int k = 1; k < 12; ++k) j += (i >= jb.start[k]) ? 1 : 0;
        const int li = i - jb.start[j];
        const float4* src = (const float4*)jb.src[j];
        float4 a = src[2 * li];
        float4 b = src[2 * li + 1];
        const int cs3 = jb.cs3[j];
        int row = li >> cs3;
        int col = (li & ((1 << cs3) - 1)) * 8;
        u16x8 o;
        o[0] = f2b(a.x); o[1] = f2b(a.y); o[2] = f2b(a.z); o[3] = f2b(a.w);
        o[4] = f2b(b.x); o[5] = f2b(b.y); o[6] = f2b(b.z); o[7] = f2b(b.w);
        *(u16x8*)(jb.dst[j] + (size_t)row * jb.stride[j] + col) = o;
    }
}

extern "C" void kernel_launch(void* const* d_in, const int* in_sizes, int n_in,
                              void* d_out, int out_size, void* d_ws, size_t ws_size,
                              hipStream_t stream) {
    const float* x     = (const float*)d_in[0];
    const float* hprev = (const float*)d_in[1];
    const float* c     = (const float*)d_in[2];
    const float* Wh    = (const float*)d_in[3];
    const float* Wz    = (const float*)d_in[4];
    const float* Wr    = (const float*)d_in[5];
    const float* Uh    = (const float*)d_in[6];
    const float* Uz    = (const float*)d_in[7];
    const float* Ur    = (const float*)d_in[8];
    const float* Ch    = (const float*)d_in[9];
    const float* Cz    = (const float*)d_in[10];
    const float* Cr    = (const float*)d_in[11];
    const float* bh    = (const float*)d_in[12];
    const float* bz    = (const float*)d_in[13];
    const float* br    = (const float*)d_in[14];

    char* ws = (char*)d_ws;
    unsigned short* Xall = (unsigned short*)ws; ws += (size_t)8192 * 4096 * 2;
    unsigned short* Wcat = (unsigned short*)ws; ws += (size_t)3072 * 4096 * 2;
    unsigned short* Uhb  = (unsigned short*)ws; ws += (size_t)1024 * 1024 * 2;
    unsigned short* rhb  = (unsigned short*)ws; ws += (size_t)8192 * 1024 * 2;
    unsigned short* shp  = (unsigned short*)ws; ws += (size_t)8192 * 1024 * 2;
    unsigned short* zsb  = (unsigned short*)ws; ws += (size_t)8192 * 1024 * 2;
    unsigned short* shpB = (unsigned short*)ws; ws += (size_t)8192 * 1024 * 2;

    CastJobs jb;
    int acc = 0;
    auto setjob = [&](int j, const float* s, unsigned short* dbase, int col0,
                      int rows, int cols, int stride) {
        jb.src[j] = s; jb.dst[j] = dbase + col0;
        jb.start[j] = acc;
        acc += rows * cols / 8;
        jb.cs3[j] = (cols == 2048) ? 8 : 7;
        jb.stride[j] = stride;
    };
    // Xall = [x | hprev | c]
    setjob(0, x,     Xall, 0,    8192, 1024, 4096);
    setjob(1, hprev, Xall, 1024, 8192, 1024, 4096);
    setjob(2, c,     Xall, 2048, 8192, 2048, 4096);
    // Wcat rows 0..1023 = [Wr|Ur|Cr]
    setjob(3, Wr, Wcat, 0,    1024, 1024, 4096);
    setjob(4, Ur, Wcat, 1024, 1024, 1024, 4096);
    setjob(5, Cr, Wcat, 2048, 1024, 2048, 4096);
    // rows 1024..2047 = [Wz|Uz|Cz]
    setjob(6, Wz, Wcat + 1024 * 4096, 0,    1024, 1024, 4096);
    setjob(7, Uz, Wcat + 1024 * 4096, 1024, 1024, 1024, 4096);
    setjob(8, Cz, Wcat + 1024 * 4096, 2048, 1024, 2048, 4096);
    // rows 2048..3071 = [Wh|unused|Ch] (dead segment never read; h k>=16 remaps +1024)
    setjob(9,  Wh, Wcat + 2048 * 4096, 0,    1024, 1024, 4096);
    setjob(10, Ch, Wcat + 2048 * 4096, 2048, 1024, 2048, 4096);
    // Uh standalone
    setjob(11, Uh, Uhb, 0, 1024, 1024, 1024);
    jb.start[12] = acc;

    hipLaunchKernelGGL(cast_all, dim3(2048), dim3(256), 0, stream, jb, acc);
    hipLaunchKernelGGL(gemm1, dim3(2048), dim3(256), 0, stream,
                       Xall, Wcat, hprev, br, bz, rhb, zsb, shp, shpB);
    hipLaunchKernelGGL(gemm2, dim3(8, 64), dim3(256), 0, stream,
                       rhb, Uhb, shp, shpB, bh, zsb, hprev, (float*)d_out);
}

// Round 5
// 446.304 us; speedup vs baseline: 1.0943x; 1.0615x over previous
//
#include <hip/hip_runtime.h>
#include <hip/hip_bf16.h>

typedef __attribute__((ext_vector_type(8))) short bf16x8;
typedef __attribute__((ext_vector_type(8))) unsigned short u16x8;
typedef __attribute__((ext_vector_type(4))) float f32x4;

#define BM 128
#define BN 128
#define BK 64

__device__ __forceinline__ unsigned short f2b(float f) {
    union { float f; unsigned int u; } x; x.f = f;
    unsigned int r = x.u + 0x7fffu + ((x.u >> 16) & 1u);
    return (unsigned short)(r >> 16);
}
__device__ __forceinline__ float b2f(unsigned short b) {
    union { unsigned int u; float f; } x; x.u = ((unsigned int)b) << 16;
    return x.f;
}

__device__ __forceinline__ float sigmoidf_(float v) {
    return 1.0f / (1.0f + __expf(-v));
}
__device__ __forceinline__ float tanhf_(float v) {
    return 1.0f - 2.0f / (__expf(2.0f * v) + 1.0f);
}

__device__ __forceinline__ void gll16(const void* g, void* l) {
    __builtin_amdgcn_global_load_lds(
        (const __attribute__((address_space(1))) void*)g,
        (__attribute__((address_space(3))) void*)l,
        16, 0, 0);
}

// Core: C[128x128] tile of A(M x lda) * B(N x ldb)^T, both bf16 K-contiguous.
// 4 waves, each 64x64 via 4x4 grid of 16x16x32 MFMAs.
// ROUND-0 CHAMPION CORE (435us, 188us gemm1, MfmaUtil 47%): 2 barriers/K-step,
// vmcnt(0) drain; 4 co-resident blocks/CU at staggered K-phases cover each other's
// drains (m114). r1-r4 lesson: every variant with fewer blocks/CU or a wider
// per-XCD A-footprint regressed (218/278/238/225 us). Do not restructure.
// LDS is XOR-swizzled (conflict-free, SQ_LDS_BANK_CONFLICT==0 verified r0-r4):
// physical 16B-block p in row r holds global column-block p ^ (r&7).
// ONLY delta vs round 0: s_setprio(1) around the MFMA burst — staggered multi-block
// regime is where setprio measurably helps (m191); isolated here for a clean A/B.
__device__ __forceinline__ void mma_core(
    const unsigned short* __restrict__ A, int lda,
    const unsigned short* __restrict__ B, int ldb,
    int m0, int n0, int nk, int remap_from, int remap_add,
    unsigned short* As, unsigned short* Bs, f32x4 acc[4][4])
{
    const int t = threadIdx.x;
    const int lane = t & 63;
    const int wm = (t >> 7) & 1;
    const int wn = (t >> 6) & 1;
    const int srow = t >> 3;                         // staging row (0..31)
    const int ldsCol = (t & 7) * 8;                  // physical LDS col (elems)
    const int swc = (((t & 7) ^ ((t >> 3) & 7))) * 8;  // swizzled global col

    for (int kt = 0; kt < nk; ++kt) {
        int k0 = kt * BK + (kt >= remap_from ? remap_add : 0);
        __syncthreads();
        #pragma unroll
        for (int j = 0; j < 4; ++j) {
            int row = j * 32 + srow;
            gll16(A + (size_t)(m0 + row) * lda + k0 + swc, As + row * BK + ldsCol);
            gll16(B + (size_t)(n0 + row) * ldb + k0 + swc, Bs + row * BK + ldsCol);
        }
        __syncthreads();
        #pragma unroll
        for (int kk = 0; kk < 2; ++kk) {
            bf16x8 af[4], bfr[4];
            // fragment row r satisfies r&7 == lane&7, so swizzle is (lane&7)
            const int off = (((kk * 4 + (lane >> 4)) ^ (lane & 7))) * 8;
            const int ra = (wm * 64 + (lane & 15)) * BK + off;
            const int rb = (wn * 64 + (lane & 15)) * BK + off;
            #pragma unroll
            for (int i = 0; i < 4; ++i)
                af[i] = *(const bf16x8*)(As + ra + i * 16 * BK);
            #pragma unroll
            for (int j = 0; j < 4; ++j)
                bfr[j] = *(const bf16x8*)(Bs + rb + j * 16 * BK);
            __builtin_amdgcn_s_setprio(1);
            #pragma unroll
            for (int i = 0; i < 4; ++i)
                #pragma unroll
                for (int j = 0; j < 4; ++j)
                    acc[i][j] = __builtin_amdgcn_mfma_f32_16x16x32_bf16(
                        af[i], bfr[j], acc[i][j], 0, 0, 0);
            __builtin_amdgcn_s_setprio(0);
        }
    }
}

// GEMM1: S = Xall(8192x4096) @ Wcat(3072x4096)^T, fused gate epilogues.
// grid = 1536 linear blocks; XCD-swizzled; gate-balanced bn interleave.
// Each XCD: contiguous 16-bm stripe x 12 interleaved bn columns (4 per gate) —
// this mapping's A-locality is what r3/r4's remap broke (FETCH 336->688 MB).
// (256,4): regs fit exactly at 64 VGPR + 64 AGPR = 128 -> 4 blocks/CU.
__global__ __launch_bounds__(256, 4) void gemm1(
    const unsigned short* __restrict__ Xall,
    const unsigned short* __restrict__ Wcat,
    const float* __restrict__ hprev,
    const float* __restrict__ br, const float* __restrict__ bz,
    unsigned short* __restrict__ rh,   // bf16 8192x1024
    unsigned short* __restrict__ zs,   // bf16 8192x1024
    unsigned short* __restrict__ shp)  // bf16 8192x1024 (gate-h partial preact)
{
    __shared__ __attribute__((aligned(16))) unsigned short As[BM * BK];
    __shared__ __attribute__((aligned(16))) unsigned short Bs[BN * BK];
    f32x4 acc[4][4] = {};

    // XCD swizzle: consecutive flat ids round-robin XCDs; each XCD gets a
    // contiguous 16bm stripe x 12 interleaved bn columns (4 per gate).
    const int flat = blockIdx.y * gridDim.x + blockIdx.x;
    const int xcd = flat & 7;
    const int p = flat >> 3;                 // 0..191
    const int bm = (xcd >> 1) * 16 + (p & 15);
    const int bn = (p >> 4) * 2 + (xcd & 1); // 12 columns, stride 2

    const int gate = (bn * BN) >> 10;        // 0=r, 1=z, 2=h
    const int m0 = bm * BM, n0 = bn * BN;
    const int nk = (gate == 2) ? 48 : 64;    // gate h skips dead Uh segment
    const int rfrom = (gate == 2) ? 16 : (1 << 30);

    mma_core(Xall, 4096, Wcat, 4096, m0, n0, nk, rfrom, 1024, As, Bs, acc);

    const int lane = threadIdx.x & 63;
    const int wm = (threadIdx.x >> 7) & 1, wn = (threadIdx.x >> 6) & 1;
    const int rowb = m0 + wm * 64 + (lane >> 4) * 4;
    const int colb = (n0 - gate * 1024) + wn * 64 + (lane & 15);

    if (gate == 0) {
        #pragma unroll
        for (int i = 0; i < 4; ++i)
            #pragma unroll
            for (int r = 0; r < 4; ++r) {
                int m = rowb + i * 16 + r;
                #pragma unroll
                for (int j = 0; j < 4; ++j) {
                    int n = colb + j * 16;
                    size_t idx = (size_t)m * 1024 + n;
                    float rr = sigmoidf_(acc[i][j][r] + br[n]);
                    rh[idx] = f2b(rr * hprev[idx]);
                }
            }
    } else if (gate == 1) {
        #pragma unroll
        for (int i = 0; i < 4; ++i)
            #pragma unroll
            for (int r = 0; r < 4; ++r) {
                int m = rowb + i * 16 + r;
                #pragma unroll
                for (int j = 0; j < 4; ++j) {
                    int n = colb + j * 16;
                    size_t idx = (size_t)m * 1024 + n;
                    zs[idx] = f2b(sigmoidf_(acc[i][j][r] + bz[n]));
                }
            }
    } else {
        #pragma unroll
        for (int i = 0; i < 4; ++i)
            #pragma unroll
            for (int r = 0; r < 4; ++r) {
                int m = rowb + i * 16 + r;
                #pragma unroll
                for (int j = 0; j < 4; ++j) {
                    int n = colb + j * 16;
                    size_t idx = (size_t)m * 1024 + n;
                    shp[idx] = f2b(acc[i][j][r]);
                }
            }
    }
}

// GEMM2: Sh2 = rh(8192x1024) @ Uhb(1024x1024)^T; epilogue computes final out.
// grid = 512 linear blocks; 8bm x 8bn region per XCD.
__global__ __launch_bounds__(256, 4) void gemm2(
    const unsigned short* __restrict__ rh,
    const unsigned short* __restrict__ Uhb,
    const unsigned short* __restrict__ shp, const float* __restrict__ bh,
    const unsigned short* __restrict__ zs,
    const float* __restrict__ hprev,
    float* __restrict__ out)           // d_out
{
    __shared__ __attribute__((aligned(16))) unsigned short As[BM * BK];
    __shared__ __attribute__((aligned(16))) unsigned short Bs[BN * BK];
    f32x4 acc[4][4] = {};

    const int flat = blockIdx.y * gridDim.x + blockIdx.x;
    const int xcd = flat & 7;
    const int p = flat >> 3;
    const int bm = xcd * 8 + (p & 7);
    const int bn = p >> 3;
    const int m0 = bm * BM, n0 = bn * BN;

    mma_core(rh, 1024, Uhb, 1024, m0, n0, 16, 1 << 30, 0, As, Bs, acc);

    const int lane = threadIdx.x & 63;
    const int wm = (threadIdx.x >> 7) & 1, wn = (threadIdx.x >> 6) & 1;
    const int rowb = m0 + wm * 64 + (lane >> 4) * 4;
    const int colb = n0 + wn * 64 + (lane & 15);

    #pragma unroll
    for (int i = 0; i < 4; ++i)
        #pragma unroll
        for (int r = 0; r < 4; ++r) {
            int m = rowb + i * 16 + r;
            #pragma unroll
            for (int j = 0; j < 4; ++j) {
                int n = colb + j * 16;
                size_t idx = (size_t)m * 1024 + n;
                float val = acc[i][j][r] + b2f(shp[idx]) + bh[n];
                float hp = tanhf_(val);
                float zv = b2f(zs[idx]);
                out[idx] = zv * hp + (1.0f - zv) * hprev[idx];
            }
        }
}

// fp32 -> bf16 strided copy-cast, 12 jobs, flat-indexed (load-balanced).
// Each flat index i handles 8 consecutive floats of its job.
struct CastJobs {
    const float* src[12];
    unsigned short* dst[12];   // pre-offset by dst col0
    int start[13];             // prefix sums in n8 units
    int cs3[12];               // log2(src cols) - 3
    int stride[12];            // dst row stride in elements
};

__global__ __launch_bounds__(256) void cast_all(CastJobs jb, int total) {
    for (int i = blockIdx.x * blockDim.x + threadIdx.x; i < total;
         i += gridDim.x * blockDim.x) {
        int j = 0;
        #pragma unroll
        for (int k = 1; k < 12; ++k) j += (i >= jb.start[k]) ? 1 : 0;
        const int li = i - jb.start[j];
        const float4* src = (const float4*)jb.src[j];
        float4 a = src[2 * li];
        float4 b = src[2 * li + 1];
        const int cs3 = jb.cs3[j];
        int row = li >> cs3;
        int col = (li & ((1 << cs3) - 1)) * 8;
        u16x8 o;
        o[0] = f2b(a.x); o[1] = f2b(a.y); o[2] = f2b(a.z); o[3] = f2b(a.w);
        o[4] = f2b(b.x); o[5] = f2b(b.y); o[6] = f2b(b.z); o[7] = f2b(b.w);
        *(u16x8*)(jb.dst[j] + (size_t)row * jb.stride[j] + col) = o;
    }
}

extern "C" void kernel_launch(void* const* d_in, const int* in_sizes, int n_in,
                              void* d_out, int out_size, void* d_ws, size_t ws_size,
                              hipStream_t stream) {
    const float* x     = (const float*)d_in[0];
    const float* hprev = (const float*)d_in[1];
    const float* c     = (const float*)d_in[2];
    const float* Wh    = (const float*)d_in[3];
    const float* Wz    = (const float*)d_in[4];
    const float* Wr    = (const float*)d_in[5];
    const float* Uh    = (const float*)d_in[6];
    const float* Uz    = (const float*)d_in[7];
    const float* Ur    = (const float*)d_in[8];
    const float* Ch    = (const float*)d_in[9];
    const float* Cz    = (const float*)d_in[10];
    const float* Cr    = (const float*)d_in[11];
    const float* bh    = (const float*)d_in[12];
    const float* bz    = (const float*)d_in[13];
    const float* br    = (const float*)d_in[14];

    char* ws = (char*)d_ws;
    unsigned short* Xall = (unsigned short*)ws; ws += (size_t)8192 * 4096 * 2;
    unsigned short* Wcat = (unsigned short*)ws; ws += (size_t)3072 * 4096 * 2;
    unsigned short* Uhb  = (unsigned short*)ws; ws += (size_t)1024 * 1024 * 2;
    unsigned short* rhb  = (unsigned short*)ws; ws += (size_t)8192 * 1024 * 2;
    unsigned short* shp  = (unsigned short*)ws; ws += (size_t)8192 * 1024 * 2;
    unsigned short* zsb  = (unsigned short*)ws; ws += (size_t)8192 * 1024 * 2;

    CastJobs jb;
    int acc = 0;
    auto setjob = [&](int j, const float* s, unsigned short* dbase, int col0,
                      int rows, int cols, int stride) {
        jb.src[j] = s; jb.dst[j] = dbase + col0;
        jb.start[j] = acc;
        acc += rows * cols / 8;
        jb.cs3[j] = (cols == 2048) ? 8 : 7;
        jb.stride[j] = stride;
    };
    // Xall = [x | hprev | c]
    setjob(0, x,     Xall, 0,    8192, 1024, 4096);
    setjob(1, hprev, Xall, 1024, 8192, 1024, 4096);
    setjob(2, c,     Xall, 2048, 8192, 2048, 4096);
    // Wcat rows 0..1023 = [Wr|Ur|Cr]
    setjob(3, Wr, Wcat, 0,    1024, 1024, 4096);
    setjob(4, Ur, Wcat, 1024, 1024, 1024, 4096);
    setjob(5, Cr, Wcat, 2048, 1024, 2048, 4096);
    // rows 1024..2047 = [Wz|Uz|Cz]
    setjob(6, Wz, Wcat + 1024 * 4096, 0,    1024, 1024, 4096);
    setjob(7, Uz, Wcat + 1024 * 4096, 1024, 1024, 1024, 4096);
    setjob(8, Cz, Wcat + 1024 * 4096, 2048, 1024, 2048, 4096);
    // rows 2048..3071 = [Wh|unused|Ch] (dead segment never read)
    setjob(9,  Wh, Wcat + 2048 * 4096, 0,    1024, 1024, 4096);
    setjob(10, Ch, Wcat + 2048 * 4096, 2048, 1024, 2048, 4096);
    // Uh standalone
    setjob(11, Uh, Uhb, 0, 1024, 1024, 1024);
    jb.start[12] = acc;

    hipLaunchKernelGGL(cast_all, dim3(2048), dim3(256), 0, stream, jb, acc);
    hipLaunchKernelGGL(gemm1, dim3(24, 64), dim3(256), 0, stream,
                       Xall, Wcat, hprev, br, bz, rhb, zsb, shp);
    hipLaunchKernelGGL(gemm2, dim3(8, 64), dim3(256), 0, stream,
                       rhb, Uhb, shp, bh, zsb, hprev, (float*)d_out);
}

// Round 6
// 445.344 us; speedup vs baseline: 1.0966x; 1.0022x over previous
//
#include <hip/hip_runtime.h>
#include <hip/hip_bf16.h>

typedef __attribute__((ext_vector_type(8))) short bf16x8;
typedef __attribute__((ext_vector_type(8))) unsigned short u16x8;
typedef __attribute__((ext_vector_type(4))) float f32x4;

#define BM 128
#define BN 128
#define BK 64

__device__ __forceinline__ unsigned short f2b(float f) {
    union { float f; unsigned int u; } x; x.f = f;
    unsigned int r = x.u + 0x7fffu + ((x.u >> 16) & 1u);
    return (unsigned short)(r >> 16);
}
__device__ __forceinline__ float b2f(unsigned short b) {
    union { unsigned int u; float f; } x; x.u = ((unsigned int)b) << 16;
    return x.f;
}

__device__ __forceinline__ float sigmoidf_(float v) {
    return 1.0f / (1.0f + __expf(-v));
}
__device__ __forceinline__ float tanhf_(float v) {
    return 1.0f - 2.0f / (__expf(2.0f * v) + 1.0f);
}

__device__ __forceinline__ void gll16(const void* g, void* l) {
    __builtin_amdgcn_global_load_lds(
        (const __attribute__((address_space(1))) void*)g,
        (__attribute__((address_space(3))) void*)l,
        16, 0, 0);
}

// Core: C[128x128] tile of A(M x lda) * B(N x ldb)^T, both bf16 K-contiguous.
// 4 waves, each 64x64 via 4x4 grid of 16x16x32 MFMAs.
// ROUND-0 CHAMPION CORE, byte-identical (188us gemm1, MfmaUtil 47%): 2 barriers/K-step,
// vmcnt(0) drain; 4 co-resident blocks/CU at staggered K-phases cover each other's
// drains (m114). Lessons r1-r5: fewer blocks/CU (r1/r2/r3), wider per-XCD A-footprint
// (r4, FETCH 2x), and setprio around the MFMA burst (r5, 188->204us: it starves the
// other blocks' staging waves) ALL regress. Do not restructure; do not reprioritize.
// LDS XOR swizzle (phys 16B-block p of row r holds global col-block p^(r&7)):
// SQ_LDS_BANK_CONFLICT == 0 verified r0-r5.
__device__ __forceinline__ void mma_core(
    const unsigned short* __restrict__ A, int lda,
    const unsigned short* __restrict__ B, int ldb,
    int m0, int n0, int nk, int kbase, int remap_from, int remap_add,
    unsigned short* As, unsigned short* Bs, f32x4 acc[4][4])
{
    const int t = threadIdx.x;
    const int lane = t & 63;
    const int wm = (t >> 7) & 1;
    const int wn = (t >> 6) & 1;
    const int srow = t >> 3;                         // staging row (0..31)
    const int ldsCol = (t & 7) * 8;                  // physical LDS col (elems)
    const int swc = (((t & 7) ^ ((t >> 3) & 7))) * 8;  // swizzled global col

    for (int kt = 0; kt < nk; ++kt) {
        int k0 = kbase + kt * BK + (kt >= remap_from ? remap_add : 0);
        __syncthreads();
        #pragma unroll
        for (int j = 0; j < 4; ++j) {
            int row = j * 32 + srow;
            gll16(A + (size_t)(m0 + row) * lda + k0 + swc, As + row * BK + ldsCol);
            gll16(B + (size_t)(n0 + row) * ldb + k0 + swc, Bs + row * BK + ldsCol);
        }
        __syncthreads();
        #pragma unroll
        for (int kk = 0; kk < 2; ++kk) {
            bf16x8 af[4], bfr[4];
            // fragment row r satisfies r&7 == lane&7, so swizzle is (lane&7)
            const int off = (((kk * 4 + (lane >> 4)) ^ (lane & 7))) * 8;
            const int ra = (wm * 64 + (lane & 15)) * BK + off;
            const int rb = (wn * 64 + (lane & 15)) * BK + off;
            #pragma unroll
            for (int i = 0; i < 4; ++i)
                af[i] = *(const bf16x8*)(As + ra + i * 16 * BK);
            #pragma unroll
            for (int j = 0; j < 4; ++j)
                bfr[j] = *(const bf16x8*)(Bs + rb + j * 16 * BK);
            #pragma unroll
            for (int i = 0; i < 4; ++i)
                #pragma unroll
                for (int j = 0; j < 4; ++j)
                    acc[i][j] = __builtin_amdgcn_mfma_f32_16x16x32_bf16(
                        af[i], bfr[j], acc[i][j], 0, 0, 0);
        }
    }
}

// GEMM1: S = Xall(8192x4096) @ Wcat(3072x4096)^T, fused gate epilogues.
// Grid = 2048 flat blocks, r0 locality mapping + h-gate SPLIT-K tail packing.
// Per XCD (f&7): 256 jobs, bm = (xcd>>1)*16 + (p&15) (A-stripe shared by an XCD pair,
// EXACTLY r0 — r4 proved changing this doubles FETCH).
//   p < 128 : rz, bn = (p>>4)*2 + (xcd&1) (8 interleaved columns/XCD), nk=64. r0-identical.
//   p >= 128: h column (p>>5 -> 4 columns/XCD, r0-identical) split into 2 K-slices
//             of nk=24 ((p>>4)&1): slice0 = Wh k0..1023 + Ch k2048..2559 (rfrom=16,+1024);
//             slice1 = Ch k2560..4095 (kbase=2560). Writes shp0/shp1; gemm2 sums.
// Tail packing: r0 ran 64 h jobs (48 steps) in 128 slots -> half idle; split gives 128
// h-halves (24 steps) -> makespan 64+24=88 step-units vs r0's 64+48=112 (ideal=88).
// Split-K numerics verified r1-r3 (absmax unchanged). h (short) jobs dispatch LAST.
// (256,4): 64 VGPR + 64 AGPR = 128 regs -> exactly 4 blocks/CU.
__global__ __launch_bounds__(256, 4) void gemm1(
    const unsigned short* __restrict__ Xall,
    const unsigned short* __restrict__ Wcat,
    const float* __restrict__ hprev,
    const float* __restrict__ br, const float* __restrict__ bz,
    unsigned short* __restrict__ rh,    // bf16 8192x1024
    unsigned short* __restrict__ zs,    // bf16 8192x1024
    unsigned short* __restrict__ shp0,  // bf16 8192x1024 (h preact, K-slice 0)
    unsigned short* __restrict__ shp1)  // bf16 8192x1024 (h preact, K-slice 1)
{
    __shared__ __attribute__((aligned(16))) unsigned short As[BM * BK];
    __shared__ __attribute__((aligned(16))) unsigned short Bs[BN * BK];
    f32x4 acc[4][4] = {};

    const int flat = blockIdx.x;
    const int xcd = flat & 7;
    const int p = flat >> 3;                 // 0..255
    const int bm = (xcd >> 1) * 16 + (p & 15);
    const int m0 = bm * BM;

    int bn, nkt, kbase, rfrom, hslice = -1;
    if (p < 128) {                           // r/z, r0-identical mapping
        bn = (p >> 4) * 2 + (xcd & 1);       // 0..15
        nkt = 64; kbase = 0; rfrom = 1 << 30;
    } else {                                 // h, split-K
        const int q = p - 128;               // 0..127
        bn = 16 + (q >> 5) * 2 + (xcd & 1);  // 16..23 (same 4 columns/XCD as r0)
        hslice = (q >> 4) & 1;
        nkt = 24;
        if (hslice == 0) { kbase = 0;    rfrom = 16; }      // Wh + Ch[:,0:512]
        else             { kbase = 2560; rfrom = 1 << 30; } // Ch[:,512:2048]
    }
    const int n0 = bn * BN;

    mma_core(Xall, 4096, Wcat, 4096, m0, n0, nkt, kbase, rfrom, 1024, As, Bs, acc);

    const int lane = threadIdx.x & 63;
    const int wm = (threadIdx.x >> 7) & 1, wn = (threadIdx.x >> 6) & 1;
    const int rowb = m0 + wm * 64 + (lane >> 4) * 4;

    if (hslice < 0) {
        const int gate = bn >> 3;                      // 0=r, 1=z
        const int colb = (n0 - gate * 1024) + wn * 64 + (lane & 15);
        if (gate == 0) {
            #pragma unroll
            for (int i = 0; i < 4; ++i)
                #pragma unroll
                for (int r = 0; r < 4; ++r) {
                    const int m = rowb + i * 16 + r;
                    #pragma unroll
                    for (int j = 0; j < 4; ++j) {
                        const int n = colb + j * 16;
                        const size_t idx = (size_t)m * 1024 + n;
                        const float rr = sigmoidf_(acc[i][j][r] + br[n]);
                        rh[idx] = f2b(rr * hprev[idx]);
                    }
                }
        } else {
            #pragma unroll
            for (int i = 0; i < 4; ++i)
                #pragma unroll
                for (int r = 0; r < 4; ++r) {
                    const int m = rowb + i * 16 + r;
                    #pragma unroll
                    for (int j = 0; j < 4; ++j) {
                        const int n = colb + j * 16;
                        const size_t idx = (size_t)m * 1024 + n;
                        zs[idx] = f2b(sigmoidf_(acc[i][j][r] + bz[n]));
                    }
                }
        }
    } else {
        unsigned short* __restrict__ dst = hslice ? shp1 : shp0;
        const int colb = (n0 - 2048) + wn * 64 + (lane & 15);
        #pragma unroll
        for (int i = 0; i < 4; ++i)
            #pragma unroll
            for (int r = 0; r < 4; ++r) {
                const int m = rowb + i * 16 + r;
                #pragma unroll
                for (int j = 0; j < 4; ++j) {
                    const int n = colb + j * 16;
                    dst[(size_t)m * 1024 + n] = f2b(acc[i][j][r]);
                }
            }
    }
}

// GEMM2: Sh2 = rh(8192x1024) @ Uhb(1024x1024)^T;
// epilogue: out = z*tanh(Sh2 + shp0 + shp1 + bh) + (1-z)*hprev.  (split-K combine)
// grid = 512 linear blocks; 8bm x 8bn region per XCD.
__global__ __launch_bounds__(256, 4) void gemm2(
    const unsigned short* __restrict__ rh,
    const unsigned short* __restrict__ Uhb,
    const unsigned short* __restrict__ shp0,
    const unsigned short* __restrict__ shp1,
    const float* __restrict__ bh,
    const unsigned short* __restrict__ zs,
    const float* __restrict__ hprev,
    float* __restrict__ out)           // d_out
{
    __shared__ __attribute__((aligned(16))) unsigned short As[BM * BK];
    __shared__ __attribute__((aligned(16))) unsigned short Bs[BN * BK];
    f32x4 acc[4][4] = {};

    const int flat = blockIdx.y * gridDim.x + blockIdx.x;
    const int xcd = flat & 7;
    const int p = flat >> 3;
    const int bm = xcd * 8 + (p & 7);
    const int bn = p >> 3;
    const int m0 = bm * BM, n0 = bn * BN;

    mma_core(rh, 1024, Uhb, 1024, m0, n0, 16, 0, 1 << 30, 0, As, Bs, acc);

    const int lane = threadIdx.x & 63;
    const int wm = (threadIdx.x >> 7) & 1, wn = (threadIdx.x >> 6) & 1;
    const int rowb = m0 + wm * 64 + (lane >> 4) * 4;
    const int colb = n0 + wn * 64 + (lane & 15);

    #pragma unroll
    for (int i = 0; i < 4; ++i)
        #pragma unroll
        for (int r = 0; r < 4; ++r) {
            int m = rowb + i * 16 + r;
            #pragma unroll
            for (int j = 0; j < 4; ++j) {
                int n = colb + j * 16;
                size_t idx = (size_t)m * 1024 + n;
                float val = acc[i][j][r] + b2f(shp0[idx]) + b2f(shp1[idx]) + bh[n];
                float hp = tanhf_(val);
                float zv = b2f(zs[idx]);
                out[idx] = zv * hp + (1.0f - zv) * hprev[idx];
            }
        }
}

// fp32 -> bf16 strided copy-cast, 12 jobs, flat-indexed (load-balanced).
// Each flat index i handles 8 consecutive floats of its job.
struct CastJobs {
    const float* src[12];
    unsigned short* dst[12];   // pre-offset by dst col0
    int start[13];             // prefix sums in n8 units
    int cs3[12];               // log2(src cols) - 3
    int stride[12];            // dst row stride in elements
};

__global__ __launch_bounds__(256) void cast_all(CastJobs jb, int total) {
    for (int i = blockIdx.x * blockDim.x + threadIdx.x; i < total;
         i += gridDim.x * blockDim.x) {
        int j = 0;
        #pragma unroll
        for (int k = 1; k < 12; ++k) j += (i >= jb.start[k]) ? 1 : 0;
        const int li = i - jb.start[j];
        const float4* src = (const float4*)jb.src[j];
        float4 a = src[2 * li];
        float4 b = src[2 * li + 1];
        const int cs3 = jb.cs3[j];
        int row = li >> cs3;
        int col = (li & ((1 << cs3) - 1)) * 8;
        u16x8 o;
        o[0] = f2b(a.x); o[1] = f2b(a.y); o[2] = f2b(a.z); o[3] = f2b(a.w);
        o[4] = f2b(b.x); o[5] = f2b(b.y); o[6] = f2b(b.z); o[7] = f2b(b.w);
        *(u16x8*)(jb.dst[j] + (size_t)row * jb.stride[j] + col) = o;
    }
}

extern "C" void kernel_launch(void* const* d_in, const int* in_sizes, int n_in,
                              void* d_out, int out_size, void* d_ws, size_t ws_size,
                              hipStream_t stream) {
    const float* x     = (const float*)d_in[0];
    const float* hprev = (const float*)d_in[1];
    const float* c     = (const float*)d_in[2];
    const float* Wh    = (const float*)d_in[3];
    const float* Wz    = (const float*)d_in[4];
    const float* Wr    = (const float*)d_in[5];
    const float* Uh    = (const float*)d_in[6];
    const float* Uz    = (const float*)d_in[7];
    const float* Ur    = (const float*)d_in[8];
    const float* Ch    = (const float*)d_in[9];
    const float* Cz    = (const float*)d_in[10];
    const float* Cr    = (const float*)d_in[11];
    const float* bh    = (const float*)d_in[12];
    const float* bz    = (const float*)d_in[13];
    const float* br    = (const float*)d_in[14];

    char* ws = (char*)d_ws;
    unsigned short* Xall = (unsigned short*)ws; ws += (size_t)8192 * 4096 * 2;
    unsigned short* Wcat = (unsigned short*)ws; ws += (size_t)3072 * 4096 * 2;
    unsigned short* Uhb  = (unsigned short*)ws; ws += (size_t)1024 * 1024 * 2;
    unsigned short* rhb  = (unsigned short*)ws; ws += (size_t)8192 * 1024 * 2;
    unsigned short* shp  = (unsigned short*)ws; ws += (size_t)8192 * 1024 * 2;
    unsigned short* zsb  = (unsigned short*)ws; ws += (size_t)8192 * 1024 * 2;
    unsigned short* shpB = (unsigned short*)ws; ws += (size_t)8192 * 1024 * 2;

    CastJobs jb;
    int acc = 0;
    auto setjob = [&](int j, const float* s, unsigned short* dbase, int col0,
                      int rows, int cols, int stride) {
        jb.src[j] = s; jb.dst[j] = dbase + col0;
        jb.start[j] = acc;
        acc += rows * cols / 8;
        jb.cs3[j] = (cols == 2048) ? 8 : 7;
        jb.stride[j] = stride;
    };
    // Xall = [x | hprev | c]
    setjob(0, x,     Xall, 0,    8192, 1024, 4096);
    setjob(1, hprev, Xall, 1024, 8192, 1024, 4096);
    setjob(2, c,     Xall, 2048, 8192, 2048, 4096);
    // Wcat rows 0..1023 = [Wr|Ur|Cr]
    setjob(3, Wr, Wcat, 0,    1024, 1024, 4096);
    setjob(4, Ur, Wcat, 1024, 1024, 1024, 4096);
    setjob(5, Cr, Wcat, 2048, 1024, 2048, 4096);
    // rows 1024..2047 = [Wz|Uz|Cz]
    setjob(6, Wz, Wcat + 1024 * 4096, 0,    1024, 1024, 4096);
    setjob(7, Uz, Wcat + 1024 * 4096, 1024, 1024, 1024, 4096);
    setjob(8, Cz, Wcat + 1024 * 4096, 2048, 1024, 2048, 4096);
    // rows 2048..3071 = [Wh|unused|Ch] (dead segment never read; h slices remap/offset)
    setjob(9,  Wh, Wcat + 2048 * 4096, 0,    1024, 1024, 4096);
    setjob(10, Ch, Wcat + 2048 * 4096, 2048, 1024, 2048, 4096);
    // Uh standalone
    setjob(11, Uh, Uhb, 0, 1024, 1024, 1024);
    jb.start[12] = acc;

    hipLaunchKernelGGL(cast_all, dim3(2048), dim3(256), 0, stream, jb, acc);
    hipLaunchKernelGGL(gemm1, dim3(2048), dim3(256), 0, stream,
                       Xall, Wcat, hprev, br, bz, rhb, zsb, shp, shpB);
    hipLaunchKernelGGL(gemm2, dim3(8, 64), dim3(256), 0, stream,
                       rhb, Uhb, shp, shpB, bh, zsb, hprev, (float*)d_out);
}

// Round 7
// 425.231 us; speedup vs baseline: 1.1485x; 1.0473x over previous
//
#include <hip/hip_runtime.h>
#include <hip/hip_bf16.h>

typedef __attribute__((ext_vector_type(8))) short bf16x8;
typedef __attribute__((ext_vector_type(8))) unsigned short u16x8;
typedef __attribute__((ext_vector_type(4))) float f32x4;

#define BM 128
#define BN 128
#define BK 64

__device__ __forceinline__ unsigned short f2b(float f) {
    union { float f; unsigned int u; } x; x.f = f;
    unsigned int r = x.u + 0x7fffu + ((x.u >> 16) & 1u);
    return (unsigned short)(r >> 16);
}
__device__ __forceinline__ float b2f(unsigned short b) {
    union { unsigned int u; float f; } x; x.u = ((unsigned int)b) << 16;
    return x.f;
}

__device__ __forceinline__ float sigmoidf_(float v) {
    return 1.0f / (1.0f + __expf(-v));
}
__device__ __forceinline__ float tanhf_(float v) {
    return 1.0f - 2.0f / (__expf(2.0f * v) + 1.0f);
}

__device__ __forceinline__ void gll16(const void* g, void* l) {
    __builtin_amdgcn_global_load_lds(
        (const __attribute__((address_space(1))) void*)g,
        (__attribute__((address_space(3))) void*)l,
        16, 0, 0);
}

// Core: C[128x128] tile of A(M x lda) * B(N x ldb)^T, both bf16 K-contiguous.
// 4 waves, each 64x64 via 4x4 grid of 16x16x32 MFMAs.
// ROUND-0 CHAMPION CORE, byte-identical (188us gemm1, MfmaUtil 47%): 2 barriers/K-step,
// vmcnt(0) drain; 4 co-resident blocks/CU at staggered K-phases cover each other's
// drains (m114). Lessons r1-r6: fewer blocks/CU (r1/r2/r3), wider per-XCD A-footprint
// (r4: FETCH 2x), setprio (r5: starves co-blocks' staging), and h split-K (r6: +85MB
// FETCH, no makespan gain — tail already hidden by co-scheduling) ALL fail to beat r0.
// gemm1 is at this structure family's measured ceiling. Do not restructure.
// LDS XOR swizzle (phys 16B-block p of row r holds global col-block p^(r&7)):
// SQ_LDS_BANK_CONFLICT == 0 verified r0-r6.
__device__ __forceinline__ void mma_core(
    const unsigned short* __restrict__ A, int lda,
    const unsigned short* __restrict__ B, int ldb,
    int m0, int n0, int nk, int remap_from, int remap_add,
    unsigned short* As, unsigned short* Bs, f32x4 acc[4][4])
{
    const int t = threadIdx.x;
    const int lane = t & 63;
    const int wm = (t >> 7) & 1;
    const int wn = (t >> 6) & 1;
    const int srow = t >> 3;                         // staging row (0..31)
    const int ldsCol = (t & 7) * 8;                  // physical LDS col (elems)
    const int swc = (((t & 7) ^ ((t >> 3) & 7))) * 8;  // swizzled global col

    for (int kt = 0; kt < nk; ++kt) {
        int k0 = kt * BK + (kt >= remap_from ? remap_add : 0);
        __syncthreads();
        #pragma unroll
        for (int j = 0; j < 4; ++j) {
            int row = j * 32 + srow;
            gll16(A + (size_t)(m0 + row) * lda + k0 + swc, As + row * BK + ldsCol);
            gll16(B + (size_t)(n0 + row) * ldb + k0 + swc, Bs + row * BK + ldsCol);
        }
        __syncthreads();
        #pragma unroll
        for (int kk = 0; kk < 2; ++kk) {
            bf16x8 af[4], bfr[4];
            // fragment row r satisfies r&7 == lane&7, so swizzle is (lane&7)
            const int off = (((kk * 4 + (lane >> 4)) ^ (lane & 7))) * 8;
            const int ra = (wm * 64 + (lane & 15)) * BK + off;
            const int rb = (wn * 64 + (lane & 15)) * BK + off;
            #pragma unroll
            for (int i = 0; i < 4; ++i)
                af[i] = *(const bf16x8*)(As + ra + i * 16 * BK);
            #pragma unroll
            for (int j = 0; j < 4; ++j)
                bfr[j] = *(const bf16x8*)(Bs + rb + j * 16 * BK);
            #pragma unroll
            for (int i = 0; i < 4; ++i)
                #pragma unroll
                for (int j = 0; j < 4; ++j)
                    acc[i][j] = __builtin_amdgcn_mfma_f32_16x16x32_bf16(
                        af[i], bfr[j], acc[i][j], 0, 0, 0);
        }
    }
}

// GEMM1: S = Xall(8192x4096) @ Wcat(3072x4096)^T, fused gate epilogues.
// EXACT round-0 champion (188us, FETCH 336MB): grid = 1536 linear blocks;
// XCD-swizzled; gate-balanced bn interleave; each XCD a contiguous 16-bm stripe
// x 12 interleaved bn columns (4 per gate). (256,4): 64 VGPR + 64 AGPR -> 4 blocks/CU.
__global__ __launch_bounds__(256, 4) void gemm1(
    const unsigned short* __restrict__ Xall,
    const unsigned short* __restrict__ Wcat,
    const float* __restrict__ hprev,
    const float* __restrict__ br, const float* __restrict__ bz,
    unsigned short* __restrict__ rh,   // bf16 8192x1024
    unsigned short* __restrict__ zs,   // bf16 8192x1024
    unsigned short* __restrict__ shp)  // bf16 8192x1024 (gate-h partial preact)
{
    __shared__ __attribute__((aligned(16))) unsigned short As[BM * BK];
    __shared__ __attribute__((aligned(16))) unsigned short Bs[BN * BK];
    f32x4 acc[4][4] = {};

    const int flat = blockIdx.y * gridDim.x + blockIdx.x;
    const int xcd = flat & 7;
    const int p = flat >> 3;                 // 0..191
    const int bm = (xcd >> 1) * 16 + (p & 15);
    const int bn = (p >> 4) * 2 + (xcd & 1); // 12 columns, stride 2

    const int gate = (bn * BN) >> 10;        // 0=r, 1=z, 2=h
    const int m0 = bm * BM, n0 = bn * BN;
    const int nk = (gate == 2) ? 48 : 64;    // gate h skips dead Uh segment
    const int rfrom = (gate == 2) ? 16 : (1 << 30);

    mma_core(Xall, 4096, Wcat, 4096, m0, n0, nk, rfrom, 1024, As, Bs, acc);

    const int lane = threadIdx.x & 63;
    const int wm = (threadIdx.x >> 7) & 1, wn = (threadIdx.x >> 6) & 1;
    const int rowb = m0 + wm * 64 + (lane >> 4) * 4;
    const int colb = (n0 - gate * 1024) + wn * 64 + (lane & 15);

    if (gate == 0) {
        #pragma unroll
        for (int i = 0; i < 4; ++i)
            #pragma unroll
            for (int r = 0; r < 4; ++r) {
                int m = rowb + i * 16 + r;
                #pragma unroll
                for (int j = 0; j < 4; ++j) {
                    int n = colb + j * 16;
                    size_t idx = (size_t)m * 1024 + n;
                    float rr = sigmoidf_(acc[i][j][r] + br[n]);
                    rh[idx] = f2b(rr * hprev[idx]);
                }
            }
    } else if (gate == 1) {
        #pragma unroll
        for (int i = 0; i < 4; ++i)
            #pragma unroll
            for (int r = 0; r < 4; ++r) {
                int m = rowb + i * 16 + r;
                #pragma unroll
                for (int j = 0; j < 4; ++j) {
                    int n = colb + j * 16;
                    size_t idx = (size_t)m * 1024 + n;
                    zs[idx] = f2b(sigmoidf_(acc[i][j][r] + bz[n]));
                }
            }
    } else {
        #pragma unroll
        for (int i = 0; i < 4; ++i)
            #pragma unroll
            for (int r = 0; r < 4; ++r) {
                int m = rowb + i * 16 + r;
                #pragma unroll
                for (int j = 0; j < 4; ++j) {
                    int n = colb + j * 16;
                    size_t idx = (size_t)m * 1024 + n;
                    shp[idx] = f2b(acc[i][j][r]);
                }
            }
    }
}

// GEMM2: Sh2 = rh(8192x1024) @ Uhb(1024x1024)^T; epilogue computes final out.
// RESTRUCTURED r7: 128x64 tiles -> 1024 blocks = 4 blocks/CU (was 512 = 2/CU).
// The drain-loop core NEEDS 4-way block stagger to hide its per-step vmcnt(0) drains
// (r1/r2 lesson); gemm2 was the only kernel still running at 2-way. LDS = 16+8 = 24KB
// (4x24=96KB < 160KB/CU); ~96 regs. 4 waves: 2M x 2N, wave tile 64x32, acc[4][2].
// Swizzle invariant (frag row&7 == lane&7) holds: row offsets are multiples of 8.
// Per XCD: bm = xcd*8 + (p&7) (A-stripe local), bn = p>>3 (all 16 columns; Uh panel
// 2MB L2-resident).
__global__ __launch_bounds__(256, 4) void gemm2(
    const unsigned short* __restrict__ rh,
    const unsigned short* __restrict__ Uhb,
    const unsigned short* __restrict__ shp, const float* __restrict__ bh,
    const unsigned short* __restrict__ zs,
    const float* __restrict__ hprev,
    float* __restrict__ out)           // d_out
{
    __shared__ __attribute__((aligned(16))) unsigned short As[128 * BK];  // 16 KB
    __shared__ __attribute__((aligned(16))) unsigned short Bs[64 * BK];   // 8 KB
    f32x4 acc[4][2] = {};

    const int flat = blockIdx.x;
    const int xcd = flat & 7;
    const int p = flat >> 3;               // 0..127
    const int bm = xcd * 8 + (p & 7);      // 0..63
    const int bn = p >> 3;                 // 0..15
    const int m0 = bm * 128, n0 = bn * 64;

    const int t = threadIdx.x;
    const int lane = t & 63;
    const int wm = (t >> 7) & 1;           // M-half (64 rows)
    const int wn = (t >> 6) & 1;           // N-half (32 cols)
    const int srow = t >> 3;               // 0..31
    const int ldsCol = (t & 7) * 8;
    const int swc = ((t & 7) ^ (srow & 7)) * 8;

    const unsigned short* gA = rh  + (size_t)(m0 + srow) * 1024 + swc;
    const unsigned short* gB = Uhb + (size_t)(n0 + srow) * 1024 + swc;

    for (int kt = 0; kt < 16; ++kt) {
        const int k0 = kt * BK;
        __syncthreads();
        // A: 128 rows (4 sweeps), B: 64 rows (2 sweeps); 6 x 16B per thread.
        #pragma unroll
        for (int j = 0; j < 4; ++j)
            gll16(gA + (size_t)(j * 32) * 1024 + k0, As + (j * 32 + srow) * BK + ldsCol);
        #pragma unroll
        for (int j = 0; j < 2; ++j)
            gll16(gB + (size_t)(j * 32) * 1024 + k0, Bs + (j * 32 + srow) * BK + ldsCol);
        __syncthreads();
        #pragma unroll
        for (int kk = 0; kk < 2; ++kk) {
            bf16x8 af[4], bfr[2];
            const int off = ((kk * 4 + (lane >> 4)) ^ (lane & 7)) * 8;
            const int ra = (wm * 64 + (lane & 15)) * BK + off;
            const int rb = (wn * 32 + (lane & 15)) * BK + off;
            #pragma unroll
            for (int i = 0; i < 4; ++i)
                af[i] = *(const bf16x8*)(As + ra + i * 16 * BK);
            #pragma unroll
            for (int j = 0; j < 2; ++j)
                bfr[j] = *(const bf16x8*)(Bs + rb + j * 16 * BK);
            #pragma unroll
            for (int i = 0; i < 4; ++i)
                #pragma unroll
                for (int j = 0; j < 2; ++j)
                    acc[i][j] = __builtin_amdgcn_mfma_f32_16x16x32_bf16(
                        af[i], bfr[j], acc[i][j], 0, 0, 0);
        }
    }

    const int rowb = m0 + wm * 64 + (lane >> 4) * 4;
    const int colb = n0 + wn * 32 + (lane & 15);

    #pragma unroll
    for (int i = 0; i < 4; ++i)
        #pragma unroll
        for (int r = 0; r < 4; ++r) {
            int m = rowb + i * 16 + r;
            #pragma unroll
            for (int j = 0; j < 2; ++j) {
                int n = colb + j * 16;
                size_t idx = (size_t)m * 1024 + n;
                float val = acc[i][j][r] + b2f(shp[idx]) + bh[n];
                float hp = tanhf_(val);
                float zv = b2f(zs[idx]);
                out[idx] = zv * hp + (1.0f - zv) * hprev[idx];
            }
        }
}

// fp32 -> bf16 strided copy-cast, 12 jobs, flat-indexed (load-balanced).
// r7: each flat index handles 16 consecutive floats (64B read, 32B write) — halves
// the per-byte index-search overhead vs r0's 8-float units; same coalescing.
struct CastJobs {
    const float* src[12];
    unsigned short* dst[12];   // pre-offset by dst col0
    int start[13];             // prefix sums in n16 units
    int cs4[12];               // log2(src cols) - 4
    int stride[12];            // dst row stride in elements
};

__global__ __launch_bounds__(256) void cast_all(CastJobs jb, int total) {
    for (int i = blockIdx.x * blockDim.x + threadIdx.x; i < total;
         i += gridDim.x * blockDim.x) {
        int j = 0;
        #pragma unroll
        for (int k = 1; k < 12; ++k) j += (i >= jb.start[k]) ? 1 : 0;
        const int li = i - jb.start[j];
        const float4* src = (const float4*)jb.src[j];
        float4 a = src[4 * li];
        float4 b = src[4 * li + 1];
        float4 c = src[4 * li + 2];
        float4 d = src[4 * li + 3];
        const int cs4 = jb.cs4[j];
        int row = li >> cs4;
        int col = (li & ((1 << cs4) - 1)) * 16;
        u16x8 o0, o1;
        o0[0] = f2b(a.x); o0[1] = f2b(a.y); o0[2] = f2b(a.z); o0[3] = f2b(a.w);
        o0[4] = f2b(b.x); o0[5] = f2b(b.y); o0[6] = f2b(b.z); o0[7] = f2b(b.w);
        o1[0] = f2b(c.x); o1[1] = f2b(c.y); o1[2] = f2b(c.z); o1[3] = f2b(c.w);
        o1[4] = f2b(d.x); o1[5] = f2b(d.y); o1[6] = f2b(d.z); o1[7] = f2b(d.w);
        unsigned short* dp = jb.dst[j] + (size_t)row * jb.stride[j] + col;
        *(u16x8*)dp = o0;
        *(u16x8*)(dp + 8) = o1;
    }
}

extern "C" void kernel_launch(void* const* d_in, const int* in_sizes, int n_in,
                              void* d_out, int out_size, void* d_ws, size_t ws_size,
                              hipStream_t stream) {
    const float* x     = (const float*)d_in[0];
    const float* hprev = (const float*)d_in[1];
    const float* c     = (const float*)d_in[2];
    const float* Wh    = (const float*)d_in[3];
    const float* Wz    = (const float*)d_in[4];
    const float* Wr    = (const float*)d_in[5];
    const float* Uh    = (const float*)d_in[6];
    const float* Uz    = (const float*)d_in[7];
    const float* Ur    = (const float*)d_in[8];
    const float* Ch    = (const float*)d_in[9];
    const float* Cz    = (const float*)d_in[10];
    const float* Cr    = (const float*)d_in[11];
    const float* bh    = (const float*)d_in[12];
    const float* bz    = (const float*)d_in[13];
    const float* br    = (const float*)d_in[14];

    char* ws = (char*)d_ws;
    unsigned short* Xall = (unsigned short*)ws; ws += (size_t)8192 * 4096 * 2;
    unsigned short* Wcat = (unsigned short*)ws; ws += (size_t)3072 * 4096 * 2;
    unsigned short* Uhb  = (unsigned short*)ws; ws += (size_t)1024 * 1024 * 2;
    unsigned short* rhb  = (unsigned short*)ws; ws += (size_t)8192 * 1024 * 2;
    unsigned short* shp  = (unsigned short*)ws; ws += (size_t)8192 * 1024 * 2;
    unsigned short* zsb  = (unsigned short*)ws; ws += (size_t)8192 * 1024 * 2;

    CastJobs jb;
    int acc = 0;
    auto setjob = [&](int j, const float* s, unsigned short* dbase, int col0,
                      int rows, int cols, int stride) {
        jb.src[j] = s; jb.dst[j] = dbase + col0;
        jb.start[j] = acc;
        acc += rows * cols / 16;
        jb.cs4[j] = (cols == 2048) ? 7 : 6;
        jb.stride[j] = stride;
    };
    // Xall = [x | hprev | c]
    setjob(0, x,     Xall, 0,    8192, 1024, 4096);
    setjob(1, hprev, Xall, 1024, 8192, 1024, 4096);
    setjob(2, c,     Xall, 2048, 8192, 2048, 4096);
    // Wcat rows 0..1023 = [Wr|Ur|Cr]
    setjob(3, Wr, Wcat, 0,    1024, 1024, 4096);
    setjob(4, Ur, Wcat, 1024, 1024, 1024, 4096);
    setjob(5, Cr, Wcat, 2048, 1024, 2048, 4096);
    // rows 1024..2047 = [Wz|Uz|Cz]
    setjob(6, Wz, Wcat + 1024 * 4096, 0,    1024, 1024, 4096);
    setjob(7, Uz, Wcat + 1024 * 4096, 1024, 1024, 1024, 4096);
    setjob(8, Cz, Wcat + 1024 * 4096, 2048, 1024, 2048, 4096);
    // rows 2048..3071 = [Wh|unused|Ch] (dead segment never read)
    setjob(9,  Wh, Wcat + 2048 * 4096, 0,    1024, 1024, 4096);
    setjob(10, Ch, Wcat + 2048 * 4096, 2048, 1024, 2048, 4096);
    // Uh standalone
    setjob(11, Uh, Uhb, 0, 1024, 1024, 1024);
    jb.start[12] = acc;

    hipLaunchKernelGGL(cast_all, dim3(2048), dim3(256), 0, stream, jb, acc);
    hipLaunchKernelGGL(gemm1, dim3(24, 64), dim3(256), 0, stream,
                       Xall, Wcat, hprev, br, bz, rhb, zsb, shp);
    hipLaunchKernelGGL(gemm2, dim3(1024), dim3(256), 0, stream,
                       rhb, Uhb, shp, bh, zsb, hprev, (float*)d_out);
}